// Round 4
// baseline (720.442 us; speedup 1.0000x reference)
//
#include <hip/hip_runtime.h>
#include <cstdint>
#include <cstddef>

#define NSAMP 4096
#define KDIM  512
#define TOT   49536   // 3 * (128*128 + 128)
#define NUMN  387     // TOT / 128

typedef __attribute__((ext_vector_type(8))) __bf16 bf16x8;
typedef __attribute__((ext_vector_type(4))) __bf16 bf16x4;
typedef __attribute__((ext_vector_type(4))) float  f32x4;

#define AS1 __attribute__((address_space(1)))
#define AS3 __attribute__((address_space(3)))

// ---------------------------------------------------------------------------
// fp32 -> bf16 cast, 4 elements per thread (float4 read, 8B write)
// ---------------------------------------------------------------------------
__global__ void cast_bf16(const float* __restrict__ in, __bf16* __restrict__ out, int n4) {
    int i = blockIdx.x * blockDim.x + threadIdx.x;
    int stride = gridDim.x * blockDim.x;
    for (; i < n4; i += stride) {
        float4 v = ((const float4*)in)[i];
        bf16x4 o = { (__bf16)v.x, (__bf16)v.y, (__bf16)v.z, (__bf16)v.w };
        ((bf16x4*)out)[i] = o;
    }
}

// ---------------------------------------------------------------------------
// Hypernetwork GEMM (chunked over samples):
//   C[m][n] = sum_k A[m][k] * B[n][k] + bias[n]
// R3 structure: DOUBLE-BUFFERED LDS, one barrier per K-iter, prefetch issued
// immediately after the barrier so the compiler's vmcnt(0)-before-s_barrier
// drains loads that already had a full compute phase in flight.
//  - XCD swizzle: same n_t -> same XCD (48-tile supergroups), B reused in L2.
//  - XOR LDS swizzle: conflict-free ds_read_b128 (verified 6.3M -> 0 in R2).
//  - Non-temporal C stores: C is write-once; keep L2 for B, stop dirty-line
//    thrash (R2 measured 175MB HBM writes for a 101.5MB tensor).
// ---------------------------------------------------------------------------
__global__ __launch_bounds__(256, 4) void hyper_gemm(
    const __bf16* __restrict__ A, const __bf16* __restrict__ B,
    const float* __restrict__ bias, __bf16* __restrict__ C)
{
    __shared__ __bf16 As[2][128 * 32];
    __shared__ __bf16 Bs[2][128 * 32];

    const int tid   = threadIdx.x;
    const int lane  = tid & 63;
    const int wv    = tid >> 6;       // 0..3
    const int quad  = lane >> 4;      // 0..3
    const int r16   = lane & 15;      // 0..15
    const int waveM = wv >> 1;        // 0..1
    const int waveN = wv & 1;         // 0..1

    // ---- block swizzle: hw linear id -> (m_t, n_t); same n_t => same XCD
    const int num_m = gridDim.y;                 // chunk/128
    const int hw    = blockIdx.y * NUMN + blockIdx.x;
    const int STW   = 48;                        // n-tiles per supergroup (mult of 8)
    const int gsize = STW * num_m;
    const int group = hw / gsize;
    const int local = hw % gsize;
    const int n_base = group * STW;
    int width = NUMN - n_base; if (width > STW) width = STW;
    const int m_t = local / width;               // n-fastest within group
    const int n_t = n_base + local % width;

    const int m0 = m_t * 128;   // chunk-local row
    const int n0 = n_t * 128;

    f32x4 acc[4][4] = {};

    // staging lane geometry (constant across k)
    const int sidx0 = wv * 2 * 64 + lane;        // c=0 slot
    const int sidx1 = sidx0 + 64;                // c=1 slot
    const int srow0 = sidx0 >> 2, srow1 = sidx1 >> 2;
    const int sg0 = (sidx0 & 3) ^ ((srow0 >> 1) & 3);
    const int sg1 = (sidx1 & 3) ^ ((srow1 >> 1) & 3);
    const __bf16* gA0 = A + (size_t)(m0 + srow0) * KDIM + sg0 * 8;
    const __bf16* gA1 = A + (size_t)(m0 + srow1) * KDIM + sg1 * 8;
    const __bf16* gB0 = B + (size_t)(n0 + srow0) * KDIM + sg0 * 8;
    const __bf16* gB1 = B + (size_t)(n0 + srow1) * KDIM + sg1 * 8;
    const int ldsA0 = wv * 2 * 512;              // element offset of c=0 dest
    const int ldsA1 = ldsA0 + 512;

    const int rsw = (r16 >> 1) & 3;              // read-phase swizzle

#define STAGE(buf, kt)                                                         \
    do {                                                                       \
        const int _k0 = (kt) * 32;                                             \
        __builtin_amdgcn_global_load_lds((AS1 void*)(gA0 + _k0),               \
            (AS3 void*)(&As[(buf)][ldsA0]), 16, 0, 0);                         \
        __builtin_amdgcn_global_load_lds((AS1 void*)(gB0 + _k0),               \
            (AS3 void*)(&Bs[(buf)][ldsA0]), 16, 0, 0);                         \
        __builtin_amdgcn_global_load_lds((AS1 void*)(gA1 + _k0),               \
            (AS3 void*)(&As[(buf)][ldsA1]), 16, 0, 0);                         \
        __builtin_amdgcn_global_load_lds((AS1 void*)(gB1 + _k0),               \
            (AS3 void*)(&Bs[(buf)][ldsA1]), 16, 0, 0);                         \
    } while (0)

    STAGE(0, 0);

#pragma unroll 2
    for (int kt = 0; kt < KDIM / 32; ++kt) {
        const int cur = kt & 1;
        __syncthreads();                  // drains prefetch issued LAST iter
        if (kt + 1 < KDIM / 32) STAGE(cur ^ 1, kt + 1);

        bf16x8 af[4], bf[4];
#pragma unroll
        for (int i = 0; i < 4; ++i) {
            int r = waveM * 64 + i * 16 + r16;
            af[i] = *(const bf16x8*)(&As[cur][r * 32 + (quad ^ rsw) * 8]);
        }
#pragma unroll
        for (int j = 0; j < 4; ++j) {
            int r = waveN * 64 + j * 16 + r16;
            bf[j] = *(const bf16x8*)(&Bs[cur][r * 32 + (quad ^ rsw) * 8]);
        }

#pragma unroll
        for (int i = 0; i < 4; ++i)
#pragma unroll
            for (int j = 0; j < 4; ++j)
                acc[i][j] = __builtin_amdgcn_mfma_f32_16x16x32_bf16(af[i], bf[j], acc[i][j], 0, 0, 0);
    }
#undef STAGE

    // --- epilogue: C/D layout col=lane&15, row=(lane>>4)*4+reg.
    // Fuse bias, cast bf16, NON-TEMPORAL stores (write-once, bypass L2).
#pragma unroll
    for (int j = 0; j < 4; ++j) {
        int n = n0 + waveN * 64 + j * 16 + r16;
        float bb = bias[n];
#pragma unroll
        for (int i = 0; i < 4; ++i) {
            int mbase = m0 + waveM * 64 + i * 16 + quad * 4;
#pragma unroll
            for (int rr = 0; rr < 4; ++rr) {
                __builtin_nontemporal_store((__bf16)(acc[i][j][rr] + bb),
                                            C + (size_t)(mbase + rr) * TOT + n);
            }
        }
    }
}

// ---------------------------------------------------------------------------
// Stage 2: per-sample 3-layer MLP with hypernetwork weights from temp chunk.
// One block (256 threads = 4 waves) per sample. Wave wv handles p-range
// [wv*32, wv*32+32). Within wave: lane l, pg=l>>4 -> p = wv*32 + 4i + pg,
// qg=l&15 -> q in [8qg, 8qg+8). Every weight load is 16B (wave reads 1KB
// contiguous). Reduce: shfl_xor(16,32) intra-wave, LDS partials cross-wave.
// ---------------------------------------------------------------------------
__global__ __launch_bounds__(256) void mlp_kernel(
    const float* __restrict__ x, const __bf16* __restrict__ temp,
    float* __restrict__ out, int samp0)
{
    const int n   = samp0 + blockIdx.x;   // global sample index
    const int tid = threadIdx.x;
    const int wv  = tid >> 6;             // 0..3
    const int l   = tid & 63;
    const int pg  = l >> 4;               // 0..3
    const int qg  = l & 15;               // 0..15

    __shared__ float h[128];
    __shared__ float partial[4][128];

    if (tid < 64) ((float2*)h)[tid] = ((const float2*)(x + (size_t)n * 128))[tid];

    const __bf16* row = temp + (size_t)blockIdx.x * TOT;   // chunk-local temp row
    int cum = 0;
#pragma unroll
    for (int layer = 0; layer < 3; ++layer) {
        const __bf16* bias = row + cum;
        const __bf16* wgt  = row + cum + 128;
        float acc[8] = {0, 0, 0, 0, 0, 0, 0, 0};
        __syncthreads();   // h ready
#pragma unroll
        for (int i = 0; i < 8; ++i) {
            int p = wv * 32 + i * 4 + pg;
            bf16x8 w = *(const bf16x8*)(wgt + (size_t)p * 128 + qg * 8);
            float hp = h[p];
#pragma unroll
            for (int j = 0; j < 8; ++j) acc[j] += (float)w[j] * hp;
        }
#pragma unroll
        for (int j = 0; j < 8; ++j) {
            acc[j] += __shfl_xor(acc[j], 16);
            acc[j] += __shfl_xor(acc[j], 32);
        }
        if (pg == 0) {
#pragma unroll
            for (int j = 0; j < 8; ++j) partial[wv][qg * 8 + j] = acc[j];
        }
        __syncthreads();   // partials ready; everyone done reading h
        if (tid < 128) {
            float v = partial[0][tid] + partial[1][tid] + partial[2][tid] + partial[3][tid]
                    + (float)bias[tid];
            if (layer < 2) v = fmaxf(v, 0.f);
            h[tid] = v;
        }
        cum += 128 + 128 * 128;
    }
    __syncthreads();
    if (tid < 64) ((float2*)(out + (size_t)n * 128))[tid] = ((const float2*)h)[tid];
}

// ---------------------------------------------------------------------------
extern "C" void kernel_launch(void* const* d_in, const int* in_sizes, int n_in,
                              void* d_out, int out_size, void* d_ws, size_t ws_size,
                              hipStream_t stream) {
    const float* int_x = (const float*)d_in[0];  // 4096 x 512
    const float* x     = (const float*)d_in[1];  // 4096 x 128
    const float* W     = (const float*)d_in[2];  // 49536 x 512
    const float* b     = (const float*)d_in[3];  // 49536
    float* out = (float*)d_out;                  // 4096 x 128

    // workspace layout (bf16): A_bf (4 MB) | W_bf (50.7 MB) | temp chunk
    char* ws = (char*)d_ws;
    __bf16* A_bf = (__bf16*)ws;
    size_t offA = (size_t)NSAMP * KDIM * 2;
    __bf16* W_bf = (__bf16*)(ws + offA);
    size_t offW = offA + (size_t)TOT * KDIM * 2;
    __bf16* temp = (__bf16*)(ws + offW);

    // Adaptive chunk: largest of {1024,512,256,128} whose temp fits remaining
    // ws. Deterministic given ws_size -> identical work every call (capture-safe).
    size_t remain = (ws_size > offW) ? (ws_size - offW) : 0;
    int chunk = 128;
    for (int c = 1024; c >= 128; c >>= 1) {
        if ((size_t)c * TOT * 2 <= remain) { chunk = c; break; }
    }

    int nA4 = NSAMP * KDIM / 4;
    cast_bf16<<<(nA4 + 255) / 256, 256, 0, stream>>>(int_x, A_bf, nA4);
    int nW4 = TOT * KDIM / 4;
    cast_bf16<<<(nW4 + 255) / 256, 256, 0, stream>>>(W, W_bf, nW4);

    for (int samp0 = 0; samp0 < NSAMP; samp0 += chunk) {
        dim3 grid(NUMN, chunk / 128);   // 387 x (chunk/128)
        hyper_gemm<<<grid, 256, 0, stream>>>(A_bf + (size_t)samp0 * KDIM, W_bf, b, temp);
        mlp_kernel<<<chunk, 256, 0, stream>>>(x, temp, out, samp0);
    }
}

// Round 5
// 581.766 us; speedup vs baseline: 1.2384x; 1.2384x over previous
//
#include <hip/hip_runtime.h>
#include <cstdint>
#include <cstddef>

#define NSAMP 4096
#define KDIM  512
#define TOT   49536   // 3 * (128*128 + 128)
#define NUMN  387     // TOT / 128
#define BK    64

typedef __attribute__((ext_vector_type(8))) __bf16 bf16x8;
typedef __attribute__((ext_vector_type(4))) __bf16 bf16x4;
typedef __attribute__((ext_vector_type(4))) float  f32x4;

#define AS1 __attribute__((address_space(1)))
#define AS3 __attribute__((address_space(3)))

// ---------------------------------------------------------------------------
// fp32 -> bf16 cast, 4 elements per thread (float4 read, 8B write)
// ---------------------------------------------------------------------------
__global__ void cast_bf16(const float* __restrict__ in, __bf16* __restrict__ out, int n4) {
    int i = blockIdx.x * blockDim.x + threadIdx.x;
    int stride = gridDim.x * blockDim.x;
    for (; i < n4; i += stride) {
        float4 v = ((const float4*)in)[i];
        bf16x4 o = { (__bf16)v.x, (__bf16)v.y, (__bf16)v.z, (__bf16)v.w };
        ((bf16x4*)out)[i] = o;
    }
}

// ---------------------------------------------------------------------------
// Hypernetwork GEMM: C[m][n] = sum_k A[m][k]*B[n][k] + bias[n]
// R4: back to the R1 structure (empirically fastest base: plain block map,
// single-buffer 2-barrier K-loop, plain stores) with ONE structural change:
// BK=64 -> 8 K-iters instead of 16. The kernel is latency-bound on the
// per-iteration vmcnt(0)-before-barrier drain (~1250 cyc/iter at BK=32,
// nothing saturated); halving barrier count halves that cost.
// XOR LDS swizzle (group ^= row&7) keeps ds_read_b128 conflict-free at the
// BK=64 row geometry (unswizzled would be 16-way).
// ---------------------------------------------------------------------------
__global__ __launch_bounds__(256) void hyper_gemm(
    const __bf16* __restrict__ A, const __bf16* __restrict__ B,
    const float* __restrict__ bias, __bf16* __restrict__ C)
{
    __shared__ __bf16 As[128 * BK];   // 16 KB
    __shared__ __bf16 Bs[128 * BK];   // 16 KB

    const int tid   = threadIdx.x;
    const int lane  = tid & 63;
    const int quad  = lane >> 4;      // 0..3
    const int r16   = lane & 15;      // 0..15
    const int wv    = tid >> 6;       // 0..3
    const int waveM = wv >> 1;        // 0..1
    const int waveN = wv & 1;         // 0..1

    const int m0 = blockIdx.y * 128;  // chunk-local row
    const int n0 = blockIdx.x * 128;

    f32x4 acc[4][4] = {};

    const int rsw = r16 & 7;          // read-phase swizzle key

    for (int kt = 0; kt < KDIM / BK; ++kt) {
        const int k0 = kt * BK;
        // --- stage 128xBK A and B tiles (16 KB each): 4 rounds of 256x16B
#pragma unroll
        for (int c = 0; c < 4; ++c) {
            int idx  = c * 256 + tid;           // 0..1023; dest = idx*16B
            int row  = idx >> 3;                // 0..127
            int gsrc = (idx & 7) ^ (row & 7);   // swizzled 16B-group in row
            const __bf16* ga = A + (size_t)(m0 + row) * KDIM + (k0 + gsrc * 8);
            __builtin_amdgcn_global_load_lds((AS1 void*)ga,
                (AS3 void*)(As + (size_t)idx * 8), 16, 0, 0);
            const __bf16* gb = B + (size_t)(n0 + row) * KDIM + (k0 + gsrc * 8);
            __builtin_amdgcn_global_load_lds((AS1 void*)gb,
                (AS3 void*)(Bs + (size_t)idx * 8), 16, 0, 0);
        }
        __syncthreads();

        // --- two sub-k MFMA passes (kk = 0,1), 16 MFMA each
#pragma unroll
        for (int kk = 0; kk < 2; ++kk) {
            bf16x8 af[4], bf[4];
#pragma unroll
            for (int i = 0; i < 4; ++i) {
                int r = waveM * 64 + i * 16 + r16;
                af[i] = *(const bf16x8*)(As + r * BK + (((kk * 4 + quad) ^ rsw) * 8));
            }
#pragma unroll
            for (int j = 0; j < 4; ++j) {
                int r = waveN * 64 + j * 16 + r16;
                bf[j] = *(const bf16x8*)(Bs + r * BK + (((kk * 4 + quad) ^ rsw) * 8));
            }
#pragma unroll
            for (int i = 0; i < 4; ++i)
#pragma unroll
                for (int j = 0; j < 4; ++j)
                    acc[i][j] = __builtin_amdgcn_mfma_f32_16x16x32_bf16(af[i], bf[j], acc[i][j], 0, 0, 0);
        }
        __syncthreads();
    }

    // --- epilogue: C/D layout col=lane&15, row=(lane>>4)*4+reg. Fuse bias,
    // cast bf16, plain stores (R1's write path measured clean: 109MB/101.5MB).
#pragma unroll
    for (int j = 0; j < 4; ++j) {
        int n = n0 + waveN * 64 + j * 16 + r16;
        float bb = bias[n];
#pragma unroll
        for (int i = 0; i < 4; ++i) {
            int mbase = m0 + waveM * 64 + i * 16 + quad * 4;
#pragma unroll
            for (int rr = 0; rr < 4; ++rr) {
                C[(size_t)(mbase + rr) * TOT + n] = (__bf16)(acc[i][j][rr] + bb);
            }
        }
    }
}

// ---------------------------------------------------------------------------
// Stage 2: per-sample 3-layer MLP with hypernetwork weights from temp chunk.
// One block (256 threads = 4 waves) per sample. Wave wv handles p-range
// [wv*32, wv*32+32). Within wave: lane l, pg=l>>4 -> p = wv*32 + 4i + pg,
// qg=l&15 -> q in [8qg, 8qg+8). Every weight load is 16B (wave reads 1KB
// contiguous). Reduce: shfl_xor(16,32) intra-wave, LDS partials cross-wave.
// ---------------------------------------------------------------------------
__global__ __launch_bounds__(256) void mlp_kernel(
    const float* __restrict__ x, const __bf16* __restrict__ temp,
    float* __restrict__ out, int samp0)
{
    const int n   = samp0 + blockIdx.x;   // global sample index
    const int tid = threadIdx.x;
    const int wv  = tid >> 6;             // 0..3
    const int l   = tid & 63;
    const int pg  = l >> 4;               // 0..3
    const int qg  = l & 15;               // 0..15

    __shared__ float h[128];
    __shared__ float partial[4][128];

    if (tid < 64) ((float2*)h)[tid] = ((const float2*)(x + (size_t)n * 128))[tid];

    const __bf16* row = temp + (size_t)blockIdx.x * TOT;   // chunk-local temp row
    int cum = 0;
#pragma unroll
    for (int layer = 0; layer < 3; ++layer) {
        const __bf16* bias = row + cum;
        const __bf16* wgt  = row + cum + 128;
        float acc[8] = {0, 0, 0, 0, 0, 0, 0, 0};
        __syncthreads();   // h ready
#pragma unroll
        for (int i = 0; i < 8; ++i) {
            int p = wv * 32 + i * 4 + pg;
            bf16x8 w = *(const bf16x8*)(wgt + (size_t)p * 128 + qg * 8);
            float hp = h[p];
#pragma unroll
            for (int j = 0; j < 8; ++j) acc[j] += (float)w[j] * hp;
        }
#pragma unroll
        for (int j = 0; j < 8; ++j) {
            acc[j] += __shfl_xor(acc[j], 16);
            acc[j] += __shfl_xor(acc[j], 32);
        }
        if (pg == 0) {
#pragma unroll
            for (int j = 0; j < 8; ++j) partial[wv][qg * 8 + j] = acc[j];
        }
        __syncthreads();   // partials ready; everyone done reading h
        if (tid < 128) {
            float v = partial[0][tid] + partial[1][tid] + partial[2][tid] + partial[3][tid]
                    + (float)bias[tid];
            if (layer < 2) v = fmaxf(v, 0.f);
            h[tid] = v;
        }
        cum += 128 + 128 * 128;
    }
    __syncthreads();
    if (tid < 64) ((float2*)(out + (size_t)n * 128))[tid] = ((const float2*)h)[tid];
}

// ---------------------------------------------------------------------------
extern "C" void kernel_launch(void* const* d_in, const int* in_sizes, int n_in,
                              void* d_out, int out_size, void* d_ws, size_t ws_size,
                              hipStream_t stream) {
    const float* int_x = (const float*)d_in[0];  // 4096 x 512
    const float* x     = (const float*)d_in[1];  // 4096 x 128
    const float* W     = (const float*)d_in[2];  // 49536 x 512
    const float* b     = (const float*)d_in[3];  // 49536
    float* out = (float*)d_out;                  // 4096 x 128

    // workspace layout (bf16): A_bf (4 MB) | W_bf (50.7 MB) | temp chunk
    char* ws = (char*)d_ws;
    __bf16* A_bf = (__bf16*)ws;
    size_t offA = (size_t)NSAMP * KDIM * 2;
    __bf16* W_bf = (__bf16*)(ws + offA);
    size_t offW = offA + (size_t)TOT * KDIM * 2;
    __bf16* temp = (__bf16*)(ws + offW);

    // Adaptive chunk: largest of {1024,512,256,128} whose temp fits remaining
    // ws. Deterministic given ws_size -> identical work every call (capture-safe).
    size_t remain = (ws_size > offW) ? (ws_size - offW) : 0;
    int chunk = 128;
    for (int c = 1024; c >= 128; c >>= 1) {
        if ((size_t)c * TOT * 2 <= remain) { chunk = c; break; }
    }

    int nA4 = NSAMP * KDIM / 4;
    cast_bf16<<<(nA4 + 255) / 256, 256, 0, stream>>>(int_x, A_bf, nA4);
    int nW4 = TOT * KDIM / 4;
    cast_bf16<<<(nW4 + 255) / 256, 256, 0, stream>>>(W, W_bf, nW4);

    for (int samp0 = 0; samp0 < NSAMP; samp0 += chunk) {
        dim3 grid(NUMN, chunk / 128);   // 387 x (chunk/128)
        hyper_gemm<<<grid, 256, 0, stream>>>(A_bf + (size_t)samp0 * KDIM, W_bf, b, temp);
        mlp_kernel<<<chunk, 256, 0, stream>>>(x, temp, out, samp0);
    }
}

// Round 6
// 541.559 us; speedup vs baseline: 1.3303x; 1.0742x over previous
//
#include <hip/hip_runtime.h>
#include <cstdint>
#include <cstddef>

#define NSAMP 4096
#define KDIM  512
#define TOT   49536   // 3 * (128*128 + 128)
#define NUMN  387     // TOT / 128
#define BK    64

typedef __attribute__((ext_vector_type(8))) __bf16 bf16x8;
typedef __attribute__((ext_vector_type(4))) __bf16 bf16x4;
typedef __attribute__((ext_vector_type(4))) float  f32x4;

#define AS1 __attribute__((address_space(1)))
#define AS3 __attribute__((address_space(3)))

// ---------------------------------------------------------------------------
// fp32 -> bf16 cast, 4 elements per thread (float4 read, 8B write)
// ---------------------------------------------------------------------------
__global__ void cast_bf16(const float* __restrict__ in, __bf16* __restrict__ out, int n4) {
    int i = blockIdx.x * blockDim.x + threadIdx.x;
    int stride = gridDim.x * blockDim.x;
    for (; i < n4; i += stride) {
        float4 v = ((const float4*)in)[i];
        bf16x4 o = { (__bf16)v.x, (__bf16)v.y, (__bf16)v.z, (__bf16)v.w };
        ((bf16x4*)out)[i] = o;
    }
}

// ---------------------------------------------------------------------------
// Hypernetwork GEMM: C[m][n] = sum_k A[m][k]*B[n][k] + bias[n]
// R5 = R4 base (BK=64, single-buffer 2-barrier loop, xor LDS swizzle, plain
// stores, no launch_bounds squeeze) + two surgical changes:
//  (a) XCD-CONGRUENT block swizzle: supergroup = 8 n-tiles x num_m m-tiles;
//      within group n_loc = r%8 (== hw_id%8 == XCD), m_t = r/8. All 8 blocks
//      sharing a B-tile land on the SAME XCD, adjacently dispatched -> B
//      staging loads become per-XCD-L2 hits (~200 cyc) instead of L3/HBM
//      (~600-900 cyc). R2's supergroup map got this exactly backwards
//      (same-n_t blocks were 8-apart -> round-robined onto ALL XCDs).
//  (b) staging pointers hoisted out of the K-loop (R4's VALUBusy=29% was
//      per-iter swizzled address recompute; hoisted R3 measured 10%).
// ---------------------------------------------------------------------------
__global__ __launch_bounds__(256) void hyper_gemm(
    const __bf16* __restrict__ A, const __bf16* __restrict__ B,
    const float* __restrict__ bias, __bf16* __restrict__ C)
{
    __shared__ __bf16 As[128 * BK];   // 16 KB
    __shared__ __bf16 Bs[128 * BK];   // 16 KB

    const int tid   = threadIdx.x;
    const int lane  = tid & 63;
    const int quad  = lane >> 4;      // 0..3
    const int r16   = lane & 15;      // 0..15
    const int wv    = tid >> 6;       // 0..3
    const int waveM = wv >> 1;        // 0..1
    const int waveN = wv & 1;         // 0..1

    // ---- XCD-congruent swizzle: hw id -> (m_t, n_t)
    const int num_m = gridDim.y;                    // chunk/128
    const int id    = blockIdx.y * NUMN + blockIdx.x;
    const int gsz   = 8 * num_m;                    // supergroup block count
    const int s     = id / gsz;
    const int r     = id % gsz;
    const int base  = s * 8;
    int w = NUMN - base; if (w > 8) w = 8;          // partial last group (387%8=3)
    const int n_t = base + r % w;
    const int m_t = r / w;

    const int m0 = m_t * 128;   // chunk-local row
    const int n0 = n_t * 128;

    f32x4 acc[4][4] = {};

    // ---- per-thread staging geometry (k-invariant, hoisted)
    const __bf16* gAp[4];
    const __bf16* gBp[4];
    int ldsOff[4];
#pragma unroll
    for (int c = 0; c < 4; ++c) {
        int idx  = c * 256 + tid;           // 0..1023; dest = idx*16B
        int row  = idx >> 3;                // 0..127
        int gsrc = (idx & 7) ^ (row & 7);   // xor-swizzled 16B-group in row
        gAp[c] = A + (size_t)(m0 + row) * KDIM + gsrc * 8;
        gBp[c] = B + (size_t)(n0 + row) * KDIM + gsrc * 8;
        ldsOff[c] = idx * 8;
    }

    const int rsw = r16 & 7;          // read-phase swizzle key

    for (int kt = 0; kt < KDIM / BK; ++kt) {
        const int k0 = kt * BK;
#pragma unroll
        for (int c = 0; c < 4; ++c) {
            __builtin_amdgcn_global_load_lds((AS1 void*)(gAp[c] + k0),
                (AS3 void*)(As + ldsOff[c]), 16, 0, 0);
            __builtin_amdgcn_global_load_lds((AS1 void*)(gBp[c] + k0),
                (AS3 void*)(Bs + ldsOff[c]), 16, 0, 0);
        }
        __syncthreads();

        // --- two sub-k MFMA passes (kk = 0,1), 16 MFMA each
#pragma unroll
        for (int kk = 0; kk < 2; ++kk) {
            bf16x8 af[4], bf[4];
#pragma unroll
            for (int i = 0; i < 4; ++i) {
                int rr = waveM * 64 + i * 16 + r16;
                af[i] = *(const bf16x8*)(As + rr * BK + (((kk * 4 + quad) ^ rsw) * 8));
            }
#pragma unroll
            for (int j = 0; j < 4; ++j) {
                int rr = waveN * 64 + j * 16 + r16;
                bf[j] = *(const bf16x8*)(Bs + rr * BK + (((kk * 4 + quad) ^ rsw) * 8));
            }
#pragma unroll
            for (int i = 0; i < 4; ++i)
#pragma unroll
                for (int j = 0; j < 4; ++j)
                    acc[i][j] = __builtin_amdgcn_mfma_f32_16x16x32_bf16(af[i], bf[j], acc[i][j], 0, 0, 0);
        }
        __syncthreads();
    }

    // --- epilogue: C/D layout col=lane&15, row=(lane>>4)*4+reg. Fuse bias,
    // cast bf16, plain stores (write path measured clean: ~100MB/101.5MB).
#pragma unroll
    for (int j = 0; j < 4; ++j) {
        int n = n0 + waveN * 64 + j * 16 + r16;
        float bb = bias[n];
#pragma unroll
        for (int i = 0; i < 4; ++i) {
            int mbase = m0 + waveM * 64 + i * 16 + quad * 4;
#pragma unroll
            for (int rr = 0; rr < 4; ++rr) {
                C[(size_t)(mbase + rr) * TOT + n] = (__bf16)(acc[i][j][rr] + bb);
            }
        }
    }
}

// ---------------------------------------------------------------------------
// Stage 2: per-sample 3-layer MLP with hypernetwork weights from temp chunk.
// One block (256 threads = 4 waves) per sample. Wave wv handles p-range
// [wv*32, wv*32+32). Within wave: lane l, pg=l>>4 -> p = wv*32 + 4i + pg,
// qg=l&15 -> q in [8qg, 8qg+8). Every weight load is 16B (wave reads 1KB
// contiguous). Reduce: shfl_xor(16,32) intra-wave, LDS partials cross-wave.
// ---------------------------------------------------------------------------
__global__ __launch_bounds__(256) void mlp_kernel(
    const float* __restrict__ x, const __bf16* __restrict__ temp,
    float* __restrict__ out, int samp0)
{
    const int n   = samp0 + blockIdx.x;   // global sample index
    const int tid = threadIdx.x;
    const int wv  = tid >> 6;             // 0..3
    const int l   = tid & 63;
    const int pg  = l >> 4;               // 0..3
    const int qg  = l & 15;               // 0..15

    __shared__ float h[128];
    __shared__ float partial[4][128];

    if (tid < 64) ((float2*)h)[tid] = ((const float2*)(x + (size_t)n * 128))[tid];

    const __bf16* row = temp + (size_t)blockIdx.x * TOT;   // chunk-local temp row
    int cum = 0;
#pragma unroll
    for (int layer = 0; layer < 3; ++layer) {
        const __bf16* bias = row + cum;
        const __bf16* wgt  = row + cum + 128;
        float acc[8] = {0, 0, 0, 0, 0, 0, 0, 0};
        __syncthreads();   // h ready
#pragma unroll
        for (int i = 0; i < 8; ++i) {
            int p = wv * 32 + i * 4 + pg;
            bf16x8 w = *(const bf16x8*)(wgt + (size_t)p * 128 + qg * 8);
            float hp = h[p];
#pragma unroll
            for (int j = 0; j < 8; ++j) acc[j] += (float)w[j] * hp;
        }
#pragma unroll
        for (int j = 0; j < 8; ++j) {
            acc[j] += __shfl_xor(acc[j], 16);
            acc[j] += __shfl_xor(acc[j], 32);
        }
        if (pg == 0) {
#pragma unroll
            for (int j = 0; j < 8; ++j) partial[wv][qg * 8 + j] = acc[j];
        }
        __syncthreads();   // partials ready; everyone done reading h
        if (tid < 128) {
            float v = partial[0][tid] + partial[1][tid] + partial[2][tid] + partial[3][tid]
                    + (float)bias[tid];
            if (layer < 2) v = fmaxf(v, 0.f);
            h[tid] = v;
        }
        cum += 128 + 128 * 128;
    }
    __syncthreads();
    if (tid < 64) ((float2*)(out + (size_t)n * 128))[tid] = ((const float2*)h)[tid];
}

// ---------------------------------------------------------------------------
extern "C" void kernel_launch(void* const* d_in, const int* in_sizes, int n_in,
                              void* d_out, int out_size, void* d_ws, size_t ws_size,
                              hipStream_t stream) {
    const float* int_x = (const float*)d_in[0];  // 4096 x 512
    const float* x     = (const float*)d_in[1];  // 4096 x 128
    const float* W     = (const float*)d_in[2];  // 49536 x 512
    const float* b     = (const float*)d_in[3];  // 49536
    float* out = (float*)d_out;                  // 4096 x 128

    // workspace layout (bf16): A_bf (4 MB) | W_bf (50.7 MB) | temp chunk
    char* ws = (char*)d_ws;
    __bf16* A_bf = (__bf16*)ws;
    size_t offA = (size_t)NSAMP * KDIM * 2;
    __bf16* W_bf = (__bf16*)(ws + offA);
    size_t offW = offA + (size_t)TOT * KDIM * 2;
    __bf16* temp = (__bf16*)(ws + offW);

    // Adaptive chunk: largest of {1024,512,256,128} whose temp fits remaining
    // ws. Deterministic given ws_size -> identical work every call (capture-safe).
    size_t remain = (ws_size > offW) ? (ws_size - offW) : 0;
    int chunk = 128;
    for (int c = 1024; c >= 128; c >>= 1) {
        if ((size_t)c * TOT * 2 <= remain) { chunk = c; break; }
    }

    int nA4 = NSAMP * KDIM / 4;
    cast_bf16<<<(nA4 + 255) / 256, 256, 0, stream>>>(int_x, A_bf, nA4);
    int nW4 = TOT * KDIM / 4;
    cast_bf16<<<(nW4 + 255) / 256, 256, 0, stream>>>(W, W_bf, nW4);

    for (int samp0 = 0; samp0 < NSAMP; samp0 += chunk) {
        dim3 grid(NUMN, chunk / 128);   // 387 x (chunk/128)
        hyper_gemm<<<grid, 256, 0, stream>>>(A_bf + (size_t)samp0 * KDIM, W_bf, b, temp);
        mlp_kernel<<<chunk, 256, 0, stream>>>(x, temp, out, samp0);
    }
}